// Round 1
// baseline (599.054 us; speedup 1.0000x reference)
//
#include <hip/hip_runtime.h>
#include <hip/hip_bf16.h>
#include <math.h>

#define H 128
#define W 128
#define C 128
#define BATCH 2
#define NPIX (H*W)            // 16384
#define CSPLIT 4
#define CCHUNK (C/CSPLIT)     // 32
#define PART_ELEMS (CSPLIT*BATCH*27*NPIX)

// ---------------------------------------------------------------------------
// Kernel 1: offset (18ch) + modulation (9ch) 3x3 conv, channel-split x4.
// part[s][b][ch][pix] : each block owns one (s, b, 16x16 tile) -> no races.
// ---------------------------------------------------------------------------
__global__ __launch_bounds__(256) void conv27_kernel(
    const float* __restrict__ x, const float* __restrict__ w_p,
    const float* __restrict__ w_m, float* __restrict__ part)
{
  int bid  = blockIdx.x;
  int s    = bid & 3;
  int tile = (bid >> 2) & 63;
  int b    = bid >> 8;
  int i = ((tile >> 3) << 4) + (threadIdx.x >> 4);
  int j = ((tile &  7) << 4) + (threadIdx.x & 15);

  float acc[27];
#pragma unroll
  for (int o = 0; o < 27; ++o) acc[o] = 0.f;

  int rows[3] = { max(i-1,0), i, min(i+1,H-1) };
  int cols[3] = { max(j-1,0), j, min(j+1,W-1) };
  float mrow[3] = { (i-1>=0)?1.f:0.f, 1.f, (i+1<H)?1.f:0.f };
  float mcol[3] = { (j-1>=0)?1.f:0.f, 1.f, (j+1<W)?1.f:0.f };

  const float* xb = x + (long)b*C*NPIX;
  for (int cl = 0; cl < CCHUNK; ++cl) {
    int c = s*CCHUNK + cl;
    const float* xc = xb + (long)c*NPIX;
    float xv[9];
#pragma unroll
    for (int di = 0; di < 3; ++di)
#pragma unroll
      for (int dj = 0; dj < 3; ++dj)
        xv[di*3+dj] = xc[rows[di]*W + cols[dj]] * (mrow[di]*mcol[dj]);

#pragma unroll
    for (int o = 0; o < 18; ++o) {
      const float* wr = w_p + (o*C + c)*9;
#pragma unroll
      for (int n = 0; n < 9; ++n) acc[o] += xv[n]*wr[n];
    }
#pragma unroll
    for (int o = 0; o < 9; ++o) {
      const float* wr = w_m + (o*C + c)*9;
#pragma unroll
      for (int n = 0; n < 9; ++n) acc[18+o] += xv[n]*wr[n];
    }
  }
  int p = i*W + j;
  float* pout = part + (long)((s*BATCH + b)*27)*NPIX + p;
#pragma unroll
  for (int o = 0; o < 27; ++o) pout[(long)o*NPIX] = acc[o];
}

// ---------------------------------------------------------------------------
// Kernel 2: transpose w_conv (128 x 1152) -> wT (1152 x 128) so the GEMM can
// read per-k rows of 128 contiguous ocs.
// ---------------------------------------------------------------------------
__global__ __launch_bounds__(256) void wt_kernel(
    const float* __restrict__ w_conv, float* __restrict__ wT)
{
  int idx = blockIdx.x*256 + threadIdx.x;   // over 1152*128
  int k  = idx >> 7;
  int oc = idx & 127;
  wT[idx] = w_conv[oc*1152 + k];
}

// ---------------------------------------------------------------------------
// Kernel 3: fused bilinear sampling + final GEMM.
// Block = 64 pixels x 128 ocs; 256 threads, per-thread 4pix x 8oc.
// Phase 0: per-(pixel,n) corner idx + modulated bilinear weights -> LDS.
// K-loop (16 chunks of 8 channels = 72 k): stage S[72][64] in LDS, GEMM.
// ---------------------------------------------------------------------------
__global__ __launch_bounds__(256) void dcn_kernel(
    const float* __restrict__ x, const float* __restrict__ part,
    const float* __restrict__ b_p, const float* __restrict__ b_m,
    const float* __restrict__ wT, float* __restrict__ out)
{
  __shared__ int4   mIv[576];     // [n*64+pix] 4 corner spatial indices
  __shared__ float4 mWv[576];     // [n*64+pix] 4 corner weights (x modulation)
  __shared__ float  sld[72][64];  // S chunk: [k_local][pix]

  int b     = blockIdx.x >> 8;
  int pbase = (blockIdx.x & 255) << 6;
  int tid   = threadIdx.x;

  // ---- phase 0: sampling metadata ----
  for (int v = tid; v < 576; v += 256) {
    int pix = v & 63;
    int n   = v >> 6;             // 0..8
    int p   = pbase + pix;
    int i = p >> 7, j = p & 127;

    const float* pp = part + (long)b*27*NPIX + p;
    const long stride_s = (long)BATCH*27*NPIX;
    float offx = b_p[n], offy = b_p[9+n], mm = b_m[n];
#pragma unroll
    for (int s = 0; s < 4; ++s) {
      offx += pp[s*stride_s + (long)n*NPIX];
      offy += pp[s*stride_s + (long)(9+n)*NPIX];
      mm   += pp[s*stride_s + (long)(18+n)*NPIX];
    }
    float mv = 1.f/(1.f + expf(-mm));

    float px = offx + (float)(i+1) + (float)(n/3 - 1);
    float py = offy + (float)(j+1) + (float)(n%3 - 1);
    float fx = floorf(px), fy = floorf(py);
    int qltx = min(max((int)fx,     0), 129);
    int qlty = min(max((int)fy,     0), 129);
    int qrbx = min(max((int)fx + 1, 0), 129);
    int qrby = min(max((int)fy + 1, 0), 129);
    px = fminf(fmaxf(px, 0.f), 129.f);
    py = fminf(fmaxf(py, 0.f), 129.f);
    float gxl = 1.f + ((float)qltx - px);
    float gxr = 1.f - ((float)qrbx - px);
    float gyl = 1.f + ((float)qlty - py);
    float gyr = 1.f - ((float)qrby - py);

    int   qx[4] = {qltx, qrbx, qltx, qrbx};
    int   qy[4] = {qlty, qrby, qrby, qlty};
    float g [4] = {gxl*gyl, gxr*gyr, gxl*gyr, gxr*gyl};
    int   ii[4]; float ww[4];
#pragma unroll
    for (int cn = 0; cn < 4; ++cn) {
      bool valid = (qx[cn]>=1)&&(qx[cn]<=H)&&(qy[cn]>=1)&&(qy[cn]<=W);
      ii[cn] = valid ? ((qx[cn]-1)*W + (qy[cn]-1)) : 0;
      ww[cn] = valid ? g[cn]*mv : 0.f;
    }
    mIv[v] = make_int4(ii[0], ii[1], ii[2], ii[3]);
    mWv[v] = make_float4(ww[0], ww[1], ww[2], ww[3]);
  }

  float4 acc[8];
#pragma unroll
  for (int o = 0; o < 8; ++o) acc[o] = make_float4(0.f,0.f,0.f,0.f);

  int og = tid >> 4;      // 0..15 -> oc group of 8
  int pg = tid & 15;      // 0..15 -> pixel group of 4

  const float* xb = x + (long)b*C*NPIX;
  for (int cc = 0; cc < 16; ++cc) {
    __syncthreads();      // meta ready (cc=0) / previous GEMM reads done
    // ---- stage S[72][64] ----
    const float* xc = xb + (long)(cc*8)*NPIX;
#pragma unroll
    for (int t = 0; t < 18; ++t) {
      int v   = t*256 + tid;        // 0..4607
      int row = v >> 6;             // k_local 0..71
      int pix = v & 63;
      int cl  = row / 9;
      int n   = row - cl*9;
      int id  = n*64 + pix;
      const float* xp = xc + (long)cl*NPIX;
      int4   iv = mIv[id];
      float4 wv = mWv[id];
      sld[row][pix] = wv.x*xp[iv.x] + wv.y*xp[iv.y]
                    + wv.z*xp[iv.z] + wv.w*xp[iv.w];
    }
    __syncthreads();
    // ---- GEMM over this K-chunk ----
    const float* wrow = wT + (long)(cc*72)*128 + og*8;
#pragma unroll 4
    for (int kk = 0; kk < 72; ++kk) {
      float4 sv = *(const float4*)&sld[kk][pg<<2];
      float4 w0 = *(const float4*)&wrow[kk*128];
      float4 w1 = *(const float4*)&wrow[kk*128+4];
      float wv[8] = {w0.x,w0.y,w0.z,w0.w,w1.x,w1.y,w1.z,w1.w};
#pragma unroll
      for (int o = 0; o < 8; ++o) {
        acc[o].x += sv.x*wv[o];
        acc[o].y += sv.y*wv[o];
        acc[o].z += sv.z*wv[o];
        acc[o].w += sv.w*wv[o];
      }
    }
  }

  // ---- epilogue ----
  int p0 = pbase + (pg<<2);
  float* ob = out + (long)(b*C + og*8)*NPIX + p0;
#pragma unroll
  for (int o = 0; o < 8; ++o)
    *(float4*)&ob[(long)o*NPIX] = acc[o];
}

// ---------------------------------------------------------------------------
extern "C" void kernel_launch(void* const* d_in, const int* in_sizes, int n_in,
                              void* d_out, int out_size, void* d_ws, size_t ws_size,
                              hipStream_t stream) {
  const float* x      = (const float*)d_in[0];
  const float* w_p    = (const float*)d_in[1];
  const float* b_p    = (const float*)d_in[2];
  const float* w_m    = (const float*)d_in[3];
  const float* b_m    = (const float*)d_in[4];
  const float* w_conv = (const float*)d_in[5];
  float* out  = (float*)d_out;
  float* part = (float*)d_ws;                 // 14.2 MB
  float* wT   = part + PART_ELEMS;            // +590 KB  (total < 15 MB)

  conv27_kernel<<<512, 256, 0, stream>>>(x, w_p, w_m, part);
  wt_kernel<<<576, 256, 0, stream>>>(w_conv, wT);
  dcn_kernel<<<512, 256, 0, stream>>>(x, part, b_p, b_m, wT, out);
}

// Round 4
// 457.837 us; speedup vs baseline: 1.3084x; 1.3084x over previous
//
#include <hip/hip_runtime.h>
#include <hip/hip_bf16.h>
#include <math.h>

#define H 128
#define W 128
#define C 128
#define BATCH 2
#define NPIX (H*W)            // 16384
#define CSPLIT 4
#define PART_ELEMS (CSPLIT*BATCH*27*NPIX)

// ---------------------------------------------------------------------------
// Kernel 1: offset(18)+modulation(9) 3x3 conv.
// Grid 2048: 4 block-splits x 2 batch x 256 tiles(8x8 px).
// Inside block: 4 thread-subsplits of 8 channels; LDS x-halo staging;
// LDS tree-reduce across subsplits. part[s][b][27][pix], s=0..3 (32ch each).
// ---------------------------------------------------------------------------
__global__ __launch_bounds__(256) void conv27_kernel(
    const float* __restrict__ x, const float* __restrict__ w_p,
    const float* __restrict__ w_m, float* __restrict__ part)
{
  // xs[32][10][11] = 3520 floats, overlaid later with red[2][64][29] = 3712
  __shared__ float smem[3712];

  int bid  = blockIdx.x;
  int s    = bid & 3;
  int b    = (bid >> 2) & 1;
  int tile = bid >> 3;               // 0..255
  int i0   = (tile >> 4) << 3;
  int j0   = (tile & 15) << 3;
  int tid  = threadIdx.x;
  int csub = tid >> 6;               // 0..3 (wave id)
  int pl   = tid & 63;
  int li   = pl >> 3, lj = pl & 7;

  // ---- stage x halo: 32 ch x 10 x 10 (row-padded to 11) ----
  const float* xb = x + ((long)b*C + s*32)*NPIX;
  for (int t = 0; t < 13; ++t) {
    int e = t*256 + tid;
    if (e < 3200) {
      int ch  = e / 100;
      int rem = e - ch*100;
      int r   = rem / 10, cc = rem - r*10;
      int gi  = i0 - 1 + r, gj = j0 - 1 + cc;
      float v = 0.f;
      if (gi >= 0 && gi < H && gj >= 0 && gj < W)
        v = xb[(long)ch*NPIX + gi*W + gj];
      smem[ch*110 + r*11 + cc] = v;
    }
  }
  __syncthreads();

  float acc[27];
#pragma unroll
  for (int o = 0; o < 27; ++o) acc[o] = 0.f;

  for (int c8 = 0; c8 < 8; ++c8) {
    int ch = csub*8 + c8;            // local 0..31
    int cg = s*32 + ch;              // global channel
    float xv[9];
#pragma unroll
    for (int di = 0; di < 3; ++di)
#pragma unroll
      for (int dj = 0; dj < 3; ++dj)
        xv[di*3+dj] = smem[ch*110 + (li+di)*11 + (lj+dj)];

#pragma unroll
    for (int o = 0; o < 18; ++o) {
      const float* wr = w_p + (o*C + cg)*9;      // wave-uniform -> s_load
#pragma unroll
      for (int n = 0; n < 9; ++n) acc[o] += xv[n]*wr[n];
    }
#pragma unroll
    for (int o = 0; o < 9; ++o) {
      const float* wr = w_m + (o*C + cg)*9;
#pragma unroll
      for (int n = 0; n < 9; ++n) acc[18+o] += xv[n]*wr[n];
    }
  }

  // ---- tree reduce across csub (reuse smem as red[2][64][29]) ----
  __syncthreads();
  if (csub >= 2) {
    float* r = smem + (csub-2)*64*29 + pl*29;
#pragma unroll
    for (int o = 0; o < 27; ++o) r[o] = acc[o];
  }
  __syncthreads();
  if (csub < 2) {
    const float* r = smem + csub*64*29 + pl*29;
#pragma unroll
    for (int o = 0; o < 27; ++o) acc[o] += r[o];
  }
  __syncthreads();
  if (csub == 1) {
    float* r = smem + pl*29;
#pragma unroll
    for (int o = 0; o < 27; ++o) r[o] = acc[o];
  }
  __syncthreads();
  if (csub == 0) {
    const float* r = smem + pl*29;
    int p = (i0+li)*W + (j0+lj);
    float* pout = part + ((long)(s*BATCH + b)*27)*NPIX + p;
#pragma unroll
    for (int o = 0; o < 27; ++o) pout[(long)o*NPIX] = acc[o] + r[o];
  }
}

// ---------------------------------------------------------------------------
// Kernel 2: transpose w_conv (128 x 1152) -> wT (1152 x 128)
// ---------------------------------------------------------------------------
__global__ __launch_bounds__(256) void wt_kernel(
    const float* __restrict__ w_conv, float* __restrict__ wT)
{
  int idx = blockIdx.x*256 + threadIdx.x;   // over 1152*128
  int k  = idx >> 7;
  int oc = idx & 127;
  wT[idx] = w_conv[oc*1152 + k];
}

// ---------------------------------------------------------------------------
// Kernel 3: fused bilinear sampling + final GEMM, software-pipelined.
// Block = 64 px x 128 oc, 256 thr, 4px x 8oc per thread.
// Per K-chunk (8 ch = 72 k): computeS from prefetched regs -> LDS(dbuf),
// issue next chunk's 72 gathers, raw s_barrier (lgkm drain only -- keeps
// the prefetch loads in flight), GEMM.
// ---------------------------------------------------------------------------
__global__ __launch_bounds__(256) void dcn_kernel(
    const float* __restrict__ x, const float* __restrict__ part,
    const float* __restrict__ b_p, const float* __restrict__ b_m,
    const float* __restrict__ wT, float* __restrict__ out)
{
  __shared__ int4   mIv[576];       // [n*64+pix] corner spatial indices
  __shared__ float4 mWv[576];       // [n*64+pix] corner weights (x modulation)
  __shared__ float  sld[2][72][64]; // double-buffered S chunk

  int b     = blockIdx.x >> 8;
  int pbase = (blockIdx.x & 255) << 6;
  int tid   = threadIdx.x;
  int wid   = tid >> 6;             // wave 0..3
  int lane  = tid & 63;

  // ---- phase 0: sampling metadata ----
  for (int v = tid; v < 576; v += 256) {
    int pix = v & 63;
    int n   = v >> 6;
    int p   = pbase + pix;
    int i = p >> 7, j = p & 127;

    const float* pp = part + (long)b*27*NPIX + p;
    const long stride_s = (long)BATCH*27*NPIX;
    float offx = b_p[n], offy = b_p[9+n], mm = b_m[n];
#pragma unroll
    for (int s = 0; s < 4; ++s) {
      offx += pp[s*stride_s + (long)n*NPIX];
      offy += pp[s*stride_s + (long)(9+n)*NPIX];
      mm   += pp[s*stride_s + (long)(18+n)*NPIX];
    }
    float mv = 1.f/(1.f + expf(-mm));

    float px = offx + (float)(i+1) + (float)(n/3 - 1);
    float py = offy + (float)(j+1) + (float)(n%3 - 1);
    float fx = floorf(px), fy = floorf(py);
    int qltx = min(max((int)fx,     0), 129);
    int qlty = min(max((int)fy,     0), 129);
    int qrbx = min(max((int)fx + 1, 0), 129);
    int qrby = min(max((int)fy + 1, 0), 129);
    px = fminf(fmaxf(px, 0.f), 129.f);
    py = fminf(fmaxf(py, 0.f), 129.f);
    float gxl = 1.f + ((float)qltx - px);
    float gxr = 1.f - ((float)qrbx - px);
    float gyl = 1.f + ((float)qlty - py);
    float gyr = 1.f - ((float)qrby - py);

    int   qx[4] = {qltx, qrbx, qltx, qrbx};
    int   qy[4] = {qlty, qrby, qrby, qlty};
    float gw[4] = {gxl*gyl, gxr*gyr, gxl*gyr, gxr*gyl};
    int   ii[4]; float ww[4];
#pragma unroll
    for (int cn = 0; cn < 4; ++cn) {
      bool valid = (qx[cn]>=1)&&(qx[cn]<=H)&&(qy[cn]>=1)&&(qy[cn]<=W);
      ii[cn] = valid ? ((qx[cn]-1)*W + (qy[cn]-1)) : 0;
      ww[cn] = valid ? gw[cn]*mv : 0.f;
    }
    mIv[v] = make_int4(ii[0], ii[1], ii[2], ii[3]);
    mWv[v] = make_float4(ww[0], ww[1], ww[2], ww[3]);
  }
  __syncthreads();   // meta visible (full drain OK here, prologue)

  float4 acc[8];
#pragma unroll
  for (int o = 0; o < 8; ++o) acc[o] = make_float4(0.f,0.f,0.f,0.f);

  int og = tid >> 4;      // 0..15 -> oc group of 8
  int pg = tid & 15;      // 0..15 -> pixel group of 4

  const float* xb = x + (long)b*C*NPIX;
  float g[72];            // prefetch registers: 18 rows x 4 corners

#define ISSUE(CCN)                                                        \
  _Pragma("unroll")                                                       \
  for (int t = 0; t < 18; ++t) {                                          \
    int row = t*4 + wid; int cl = row/9; int n = row - cl*9;              \
    int4 iv = mIv[n*64 + lane];                                           \
    const float* xc = xb + (long)((CCN)*8 + cl)*NPIX;                     \
    g[t*4+0] = xc[iv.x]; g[t*4+1] = xc[iv.y];                             \
    g[t*4+2] = xc[iv.z]; g[t*4+3] = xc[iv.w];                             \
  }

  ISSUE(0)

  for (int cc = 0; cc < 16; ++cc) {
    int buf = cc & 1;
    // ---- computeS from prefetched regs -> LDS ----
#pragma unroll
    for (int t = 0; t < 18; ++t) {
      int row = t*4 + wid; int cl = row/9; int n = row - cl*9;
      float4 wv = mWv[n*64 + lane];
      sld[buf][row][lane] = wv.x*g[t*4+0] + wv.y*g[t*4+1]
                          + wv.z*g[t*4+2] + wv.w*g[t*4+3];
    }
    // ---- issue next chunk's gathers (stay in flight across barrier) ----
    if (cc < 15) { ISSUE(cc+1) }
    __builtin_amdgcn_sched_barrier(0);
    asm volatile("s_waitcnt lgkmcnt(0)" ::: "memory");  // ds_writes visible
    __builtin_amdgcn_sched_barrier(0);
    __builtin_amdgcn_s_barrier();                        // no vmcnt drain
    __builtin_amdgcn_sched_barrier(0);
    // ---- GEMM over this K-chunk ----
    const float* wrow = wT + (long)(cc*72)*128 + og*8;
#pragma unroll 4
    for (int kk = 0; kk < 72; ++kk) {
      float4 sv = *(const float4*)&sld[buf][kk][pg<<2];
      float4 w0 = *(const float4*)&wrow[kk*128];
      float4 w1 = *(const float4*)&wrow[kk*128+4];
      float wv[8] = {w0.x,w0.y,w0.z,w0.w,w1.x,w1.y,w1.z,w1.w};
#pragma unroll
      for (int o = 0; o < 8; ++o) {
        acc[o].x += sv.x*wv[o];
        acc[o].y += sv.y*wv[o];
        acc[o].z += sv.z*wv[o];
        acc[o].w += sv.w*wv[o];
      }
    }
  }
#undef ISSUE

  // ---- epilogue ----
  int p0 = pbase + (pg<<2);
  float* ob = out + (long)(b*C + og*8)*NPIX + p0;
#pragma unroll
  for (int o = 0; o < 8; ++o)
    *(float4*)&ob[(long)o*NPIX] = acc[o];
}

// ---------------------------------------------------------------------------
extern "C" void kernel_launch(void* const* d_in, const int* in_sizes, int n_in,
                              void* d_out, int out_size, void* d_ws, size_t ws_size,
                              hipStream_t stream) {
  const float* x      = (const float*)d_in[0];
  const float* w_p    = (const float*)d_in[1];
  const float* b_p    = (const float*)d_in[2];
  const float* w_m    = (const float*)d_in[3];
  const float* b_m    = (const float*)d_in[4];
  const float* w_conv = (const float*)d_in[5];
  float* out  = (float*)d_out;
  float* part = (float*)d_ws;                 // 14.16 MB
  float* wT   = part + PART_ELEMS;            // +0.59 MB (total < 15 MB, proven safe)

  conv27_kernel<<<2048, 256, 0, stream>>>(x, w_p, w_m, part);
  wt_kernel<<<576, 256, 0, stream>>>(w_conv, wT);
  dcn_kernel<<<512, 256, 0, stream>>>(x, part, b_p, b_m, wT, out);
}

// Round 5
// 262.620 us; speedup vs baseline: 2.2811x; 1.7433x over previous
//
#include <hip/hip_runtime.h>
#include <hip/hip_bf16.h>
#include <math.h>

#define H 128
#define W 128
#define C 128
#define BATCH 2
#define NPIX (H*W)            // 16384
#define CSPLIT 4
#define PART_ELEMS (CSPLIT*BATCH*27*NPIX)   // 3538944 floats
#define PX 32                 // pixels per dcn block

typedef __attribute__((ext_vector_type(8))) short bf16x8;   // 8 bf16 = 4 VGPR
typedef __attribute__((ext_vector_type(4))) float f32x4;

static __device__ __forceinline__ unsigned short f2bf(float f){
  unsigned u = __float_as_uint(f);
  u += 0x7FFF + ((u >> 16) & 1);          // RNE
  return (unsigned short)(u >> 16);
}

// ---------------------------------------------------------------------------
// Kernel 1: offset(18)+modulation(9) 3x3 conv. Same structure as round 4,
// but csub forced wave-uniform via readfirstlane so weight addresses are
// provably uniform -> s_load on SMEM pipe (overlaps VALU).
// ---------------------------------------------------------------------------
__global__ __launch_bounds__(256) void conv27_kernel(
    const float* __restrict__ x, const float* __restrict__ w_p,
    const float* __restrict__ w_m, float* __restrict__ part)
{
  __shared__ float smem[3712];

  int bid  = blockIdx.x;
  int s    = bid & 3;
  int b    = (bid >> 2) & 1;
  int tile = bid >> 3;
  int i0   = (tile >> 4) << 3;
  int j0   = (tile & 15) << 3;
  int tid  = threadIdx.x;
  int csub = __builtin_amdgcn_readfirstlane(tid >> 6);   // wave id, uniform
  int pl   = tid & 63;
  int li   = pl >> 3, lj = pl & 7;

  const float* xb = x + ((long)b*C + s*32)*NPIX;
  for (int t = 0; t < 13; ++t) {
    int e = t*256 + tid;
    if (e < 3200) {
      int ch  = e / 100;
      int rem = e - ch*100;
      int r   = rem / 10, cc = rem - r*10;
      int gi  = i0 - 1 + r, gj = j0 - 1 + cc;
      float v = 0.f;
      if (gi >= 0 && gi < H && gj >= 0 && gj < W)
        v = xb[(long)ch*NPIX + gi*W + gj];
      smem[ch*110 + r*11 + cc] = v;
    }
  }
  __syncthreads();

  float acc[27];
#pragma unroll
  for (int o = 0; o < 27; ++o) acc[o] = 0.f;

  for (int c8 = 0; c8 < 8; ++c8) {
    int ch = csub*8 + c8;
    int cg = s*32 + ch;                 // uniform
    float xv[9];
#pragma unroll
    for (int di = 0; di < 3; ++di)
#pragma unroll
      for (int dj = 0; dj < 3; ++dj)
        xv[di*3+dj] = smem[ch*110 + (li+di)*11 + (lj+dj)];

#pragma unroll
    for (int o = 0; o < 18; ++o) {
      const float* wr = w_p + (o*C + cg)*9;   // uniform addr -> s_load
#pragma unroll
      for (int n = 0; n < 9; ++n) acc[o] += xv[n]*wr[n];
    }
#pragma unroll
    for (int o = 0; o < 9; ++o) {
      const float* wr = w_m + (o*C + cg)*9;
#pragma unroll
      for (int n = 0; n < 9; ++n) acc[18+o] += xv[n]*wr[n];
    }
  }

  __syncthreads();
  if (csub >= 2) {
    float* r = smem + (csub-2)*64*29 + pl*29;
#pragma unroll
    for (int o = 0; o < 27; ++o) r[o] = acc[o];
  }
  __syncthreads();
  if (csub < 2) {
    const float* r = smem + csub*64*29 + pl*29;
#pragma unroll
    for (int o = 0; o < 27; ++o) acc[o] += r[o];
  }
  __syncthreads();
  if (csub == 1) {
    float* r = smem + pl*29;
#pragma unroll
    for (int o = 0; o < 27; ++o) r[o] = acc[o];
  }
  __syncthreads();
  if (csub == 0) {
    const float* r = smem + pl*29;
    int p = (i0+li)*W + (j0+lj);
    float* pout = part + ((long)(s*BATCH + b)*27)*NPIX + p;
#pragma unroll
    for (int o = 0; o < 27; ++o) pout[(long)o*NPIX] = acc[o] + r[o];
  }
}

// ---------------------------------------------------------------------------
// Kernel 2: pack w_conv (128 oc x 1152 k, fp32) into A-fragment bf16 layout:
// wPack[kq][oc][e], kq = ks*4+kslot (0..143), e=0..7, k = kq*8+e.
// Lane of the GEMM reads one contiguous bf16x8 = 16B.
// ---------------------------------------------------------------------------
__global__ __launch_bounds__(256) void wpack_kernel(
    const float* __restrict__ w_conv, unsigned short* __restrict__ wPack)
{
  int g  = blockIdx.x*256 + threadIdx.x;   // 0..18431
  int oc = g & 127;
  int kq = g >> 7;                          // 0..143
  const float* src = w_conv + oc*1152 + kq*8;
  float4 f0 = *(const float4*)src;
  float4 f1 = *(const float4*)(src+4);
  unsigned p0 = (unsigned)f2bf(f0.x) | ((unsigned)f2bf(f0.y)<<16);
  unsigned p1 = (unsigned)f2bf(f0.z) | ((unsigned)f2bf(f0.w)<<16);
  unsigned p2 = (unsigned)f2bf(f1.x) | ((unsigned)f2bf(f1.y)<<16);
  unsigned p3 = (unsigned)f2bf(f1.z) | ((unsigned)f2bf(f1.w)<<16);
  *(uint4*)(wPack + (long)g*8) = make_uint4(p0,p1,p2,p3);
}

// ---------------------------------------------------------------------------
// Kernel 3: fused bilinear sampling + MFMA GEMM.
// Block = 32 px x 128 oc, 4 waves; wave w owns oc [w*32, w*32+32).
// K = 1152 = 18 chunks of 64. Per chunk: S (fp32 gather+lerp) -> bf16 ->
// LDS in B-frag packing sP[ksl8][px][8e]; A-frags (wPack) from global.
// mfma_f32_16x16x32_bf16: A=W (M=oc), B=S (N=px), D=out[oc][px].
// Pipeline: gathers + A-frags for next chunk issued before a raw s_barrier
// (lgkm-only drain) so they stay in flight during MFMA (round-4 proven).
// ---------------------------------------------------------------------------
__global__ __launch_bounds__(256) void dcn_kernel(
    const float* __restrict__ x, const float* __restrict__ part,
    const float* __restrict__ b_p, const float* __restrict__ b_m,
    const unsigned short* __restrict__ wPack, float* __restrict__ out)
{
  __shared__ int4   mIv[9*PX];                 // corner indices
  __shared__ float4 mWv[9*PX];                 // corner weights (x modulation)
  __shared__ unsigned short sP[2][8*PX*8];     // [buf][(ksl8*PX+px)*8+e]

  int b     = blockIdx.x >> 9;
  int pbase = (blockIdx.x & 511) * PX;
  int tid   = threadIdx.x;
  int lane  = tid & 63;
  int wid   = tid >> 6;

  // ---- phase 0: sampling metadata (288 entries) ----
  for (int v = tid; v < 9*PX; v += 256) {
    int px = v & (PX-1);
    int n  = v >> 5;
    int p  = pbase + px;
    int i = p >> 7, j = p & 127;

    const float* pp = part + (long)b*27*NPIX + p;
    const long ss = (long)BATCH*27*NPIX;
    float offx = b_p[n], offy = b_p[9+n], mm = b_m[n];
#pragma unroll
    for (int s = 0; s < 4; ++s) {
      offx += pp[s*ss + (long)n*NPIX];
      offy += pp[s*ss + (long)(9+n)*NPIX];
      mm   += pp[s*ss + (long)(18+n)*NPIX];
    }
    float mv = 1.f/(1.f + expf(-mm));

    float px_ = offx + (float)(i+1) + (float)(n/3 - 1);
    float py_ = offy + (float)(j+1) + (float)(n%3 - 1);
    float fx = floorf(px_), fy = floorf(py_);
    int qltx = min(max((int)fx,     0), 129);
    int qlty = min(max((int)fy,     0), 129);
    int qrbx = min(max((int)fx + 1, 0), 129);
    int qrby = min(max((int)fy + 1, 0), 129);
    px_ = fminf(fmaxf(px_, 0.f), 129.f);
    py_ = fminf(fmaxf(py_, 0.f), 129.f);
    float gxl = 1.f + ((float)qltx - px_);
    float gxr = 1.f - ((float)qrbx - px_);
    float gyl = 1.f + ((float)qlty - py_);
    float gyr = 1.f - ((float)qrby - py_);

    int   qx[4] = {qltx, qrbx, qltx, qrbx};
    int   qy[4] = {qlty, qrby, qrby, qlty};
    float gw[4] = {gxl*gyl, gxr*gyr, gxl*gyr, gxr*gyl};
    int   ii[4]; float ww[4];
#pragma unroll
    for (int cn = 0; cn < 4; ++cn) {
      bool valid = (qx[cn]>=1)&&(qx[cn]<=H)&&(qy[cn]>=1)&&(qy[cn]<=W);
      ii[cn] = valid ? ((qx[cn]-1)*W + (qy[cn]-1)) : 0;
      ww[cn] = valid ? gw[cn]*mv : 0.f;
    }
    mIv[v] = make_int4(ii[0], ii[1], ii[2], ii[3]);
    mWv[v] = make_float4(ww[0], ww[1], ww[2], ww[3]);
  }
  __syncthreads();

  f32x4 acc[2][2];                     // [octile][pxtile], const-indexed only
#pragma unroll
  for (int a_ = 0; a_ < 2; ++a_)
#pragma unroll
    for (int b_ = 0; b_ < 2; ++b_) acc[a_][b_] = (f32x4){0.f,0.f,0.f,0.f};

  int spx   = tid & 31;                // S-producer pixel
  int ksl8  = tid >> 5;                // S-producer k-slot (0..7)
  int col   = lane & 15;               // MFMA n/m index
  int kslot = lane >> 4;               // MFMA k-slot (0..3)

  const float* xb = x + (long)b*C*NPIX;
  float g[32];                         // gather prefetch (const-indexed)
  bf16x8 aCur[2][2], aNxt[2][2];       // A-frag prefetch [kstep][octile]

#define ISSUE_G(CC) { _Pragma("unroll")                                   \
  for (int j = 0; j < 8; ++j) {                                           \
    int k = (CC)*64 + ksl8*8 + j;                                         \
    int c = (int)(((unsigned)k * 7282u) >> 16);  /* k/9 exact for k<1152 */\
    int n = k - c*9;                                                      \
    int4 iv = mIv[n*PX + spx];                                            \
    const float* xc = xb + (long)c*NPIX;                                  \
    g[j*4+0]=xc[iv.x]; g[j*4+1]=xc[iv.y];                                 \
    g[j*4+2]=xc[iv.z]; g[j*4+3]=xc[iv.w];                                 \
  } }

#define COMPUTE_S(CC, BUF) {                                              \
  unsigned pk[4];                                                         \
  _Pragma("unroll")                                                       \
  for (int jp = 0; jp < 4; ++jp) {                                        \
    float sv[2];                                                          \
    _Pragma("unroll")                                                     \
    for (int h = 0; h < 2; ++h) {                                         \
      int j = jp*2 + h;                                                   \
      int k = (CC)*64 + ksl8*8 + j;                                       \
      int c = (int)(((unsigned)k * 7282u) >> 16);                         \
      int n = k - c*9;                                                    \
      float4 wv = mWv[n*PX + spx];                                        \
      sv[h] = wv.x*g[j*4] + wv.y*g[j*4+1] + wv.z*g[j*4+2] + wv.w*g[j*4+3];\
    }                                                                     \
    pk[jp] = (unsigned)f2bf(sv[0]) | ((unsigned)f2bf(sv[1])<<16);         \
  }                                                                       \
  *(uint4*)&sP[BUF][(ksl8*PX + spx)*8] = make_uint4(pk[0],pk[1],pk[2],pk[3]); }

#define ISSUE_A(CC, DST) { _Pragma("unroll")                              \
  for (int st = 0; st < 2; ++st) { _Pragma("unroll")                      \
    for (int o2 = 0; o2 < 2; ++o2) {                                      \
      int kq = (CC)*8 + st*4 + kslot;                                     \
      int oc = wid*32 + o2*16 + col;                                      \
      DST[st][o2] = *(const bf16x8*)(wPack + ((long)kq*128 + oc)*8);      \
    } } }

#define BARRIER {                                                         \
  __builtin_amdgcn_sched_barrier(0);                                      \
  asm volatile("s_waitcnt lgkmcnt(0)" ::: "memory");                      \
  __builtin_amdgcn_sched_barrier(0);                                      \
  __builtin_amdgcn_s_barrier();                                           \
  __builtin_amdgcn_sched_barrier(0); }

#define DO_MFMA(BUF, AFR) { _Pragma("unroll")                             \
  for (int st = 0; st < 2; ++st) {                                        \
    bf16x8 b0 = *(const bf16x8*)&sP[BUF][((st*4+kslot)*PX +      col)*8]; \
    bf16x8 b1 = *(const bf16x8*)&sP[BUF][((st*4+kslot)*PX + 16 + col)*8]; \
    acc[0][0] = __builtin_amdgcn_mfma_f32_16x16x32_bf16(AFR[st][0], b0, acc[0][0], 0,0,0); \
    acc[0][1] = __builtin_amdgcn_mfma_f32_16x16x32_bf16(AFR[st][0], b1, acc[0][1], 0,0,0); \
    acc[1][0] = __builtin_amdgcn_mfma_f32_16x16x32_bf16(AFR[st][1], b0, acc[1][0], 0,0,0); \
    acc[1][1] = __builtin_amdgcn_mfma_f32_16x16x32_bf16(AFR[st][1], b1, acc[1][1], 0,0,0); \
  } }

  ISSUE_G(0)
  ISSUE_A(0, aCur)

  // 18 chunks, unrolled x2 so LDS buffer index is compile-time constant
  for (int cc2 = 0; cc2 < 9; ++cc2) {
    int ccE = cc2*2, ccO = cc2*2 + 1;

    COMPUTE_S(ccE, 0)                  // waits on g(ccE) gathers
    ISSUE_G(ccO)                       // next gathers: in flight over barrier
    BARRIER
    ISSUE_A(ccO, aNxt)                 // A-frags for odd chunk
    DO_MFMA(0, aCur)

    COMPUTE_S(ccO, 1)
    if (cc2 < 8) { ISSUE_G(ccE+2) }
    BARRIER
    if (cc2 < 8) { ISSUE_A(ccE+2, aCur) }
    DO_MFMA(1, aNxt)
  }
#undef ISSUE_G
#undef COMPUTE_S
#undef ISSUE_A
#undef BARRIER
#undef DO_MFMA

  // ---- epilogue: D col=lane&15 -> px, row=(lane>>4)*4+r -> oc ----
  int row4 = (lane >> 4) * 4;
#pragma unroll
  for (int o2 = 0; o2 < 2; ++o2)
#pragma unroll
    for (int p2 = 0; p2 < 2; ++p2)
#pragma unroll
      for (int r = 0; r < 4; ++r) {
        int oc = wid*32 + o2*16 + row4 + r;
        int px = pbase + p2*16 + col;
        out[((long)(b*C + oc))*NPIX + px] = acc[o2][p2][r];
      }
}

// ---------------------------------------------------------------------------
extern "C" void kernel_launch(void* const* d_in, const int* in_sizes, int n_in,
                              void* d_out, int out_size, void* d_ws, size_t ws_size,
                              hipStream_t stream) {
  const float* x      = (const float*)d_in[0];
  const float* w_p    = (const float*)d_in[1];
  const float* b_p    = (const float*)d_in[2];
  const float* w_m    = (const float*)d_in[3];
  const float* b_m    = (const float*)d_in[4];
  const float* w_conv = (const float*)d_in[5];
  float* out = (float*)d_out;
  float* part = (float*)d_ws;                                   // 14.16 MB
  unsigned short* wPk = (unsigned short*)((char*)d_ws + (size_t)PART_ELEMS*4); // +288 KB

  conv27_kernel<<<2048, 256, 0, stream>>>(x, w_p, w_m, part);
  wpack_kernel<<<72, 256, 0, stream>>>(w_conv, wPk);
  dcn_kernel<<<1024, 256, 0, stream>>>(x, part, b_p, b_m, wPk, out);
}

// Round 7
// 190.562 us; speedup vs baseline: 3.1436x; 1.3781x over previous
//
#include <hip/hip_runtime.h>
#include <hip/hip_bf16.h>
#include <math.h>

#define H 128
#define W 128
#define C 128
#define BATCH 2
#define NPIX (H*W)            // 16384
#define CSPLIT 4
#define PART_ELEMS (CSPLIT*BATCH*27*NPIX)   // 3538944 floats
#define PX 32                 // pixels per dcn block

// ws layout (bytes): part 14155776 | wPack 294912 | xT 16777216  = 31.2 MB
#define WS_WPK_OFF 14155776
#define WS_XT_OFF  14450688

typedef __attribute__((ext_vector_type(8))) short bf16x8;
typedef __attribute__((ext_vector_type(4))) float f32x4;

static __device__ __forceinline__ unsigned short f2bf(float f){
  unsigned u = __float_as_uint(f);
  u += 0x7FFF + ((u >> 16) & 1);          // RNE
  return (unsigned short)(u >> 16);
}

// ---------------------------------------------------------------------------
// Kernel 1: offset(18)+modulation(9) 3x3 conv + NHWC transpose of x.
// Grid 1024 = 4 s-splits x 2 batch x 128 tiles (8 rows x 16 cols).
// Thread = (csub: 8ch, pl: 2 px). Weight s_loads per wave serve 128 px
// (2x round-5 amortization). Also emits xT[b][pix][c] fp32 from the LDS halo.
// ---------------------------------------------------------------------------
__global__ __launch_bounds__(256) void conv27_kernel(
    const float* __restrict__ x, const float* __restrict__ w_p,
    const float* __restrict__ w_m, float* __restrict__ part,
    float* __restrict__ xT)
{
  __shared__ float smem[7168];   // halo 32ch x 10 x 18 = 5760; red 7168

  int bid  = blockIdx.x;
  int s    = bid & 3;
  int b    = (bid >> 2) & 1;
  int tile = bid >> 3;               // 0..127
  int i0   = (tile >> 3) << 3;       // 16 tile-rows * 8
  int j0   = (tile & 7) << 4;        // 8 tile-cols * 16
  int tid  = threadIdx.x;
  int csub = __builtin_amdgcn_readfirstlane(tid >> 6);
  int pl   = tid & 63;
  int li   = pl >> 4, lj = pl & 15;  // rows 0..3 (and +4), cols 0..15

  // ---- stage halo: 32 ch x 10 x 18 ----
  const float* xb = x + ((long)b*C + s*32)*NPIX;
  for (int t = 0; t < 23; ++t) {
    int e = t*256 + tid;
    if (e < 5760) {
      int ch = e/180; int rem = e - ch*180;
      int r  = rem/18; int cc = rem - r*18;
      int gi = i0 - 1 + r, gj = j0 - 1 + cc;
      float v = 0.f;
      if (gi >= 0 && gi < H && gj >= 0 && gj < W)
        v = xb[(long)ch*NPIX + gi*W + gj];
      smem[ch*180 + r*18 + cc] = v;
    }
  }
  __syncthreads();

  // ---- emit xT (NHWC fp32): 2 px x 8 ch per thread ----
  {
    int cbase = s*32 + csub*8;
#pragma unroll
    for (int ph = 0; ph < 2; ++ph) {
      int row = li + ph*4;
      int p   = (i0+row)*W + (j0+lj);
      const float* sp = &smem[(csub*8)*180 + (row+1)*18 + (lj+1)];
      float4 v0 = make_float4(sp[0],   sp[180], sp[360],  sp[540]);
      float4 v1 = make_float4(sp[720], sp[900], sp[1080], sp[1260]);
      float* dst = xT + ((long)b*NPIX + p)*C + cbase;
      *(float4*)dst = v0; *(float4*)(dst+4) = v1;
    }
  }

  float accA[27], accB[27];
#pragma unroll
  for (int o = 0; o < 27; ++o) { accA[o] = 0.f; accB[o] = 0.f; }

  for (int c8 = 0; c8 < 8; ++c8) {
    int ch = csub*8 + c8;
    int cg = s*32 + ch;                 // uniform -> s_load weights
    float xva[9], xvb[9];
#pragma unroll
    for (int di = 0; di < 3; ++di)
#pragma unroll
      for (int dj = 0; dj < 3; ++dj) {
        xva[di*3+dj] = smem[ch*180 + (li+di)*18   + (lj+dj)];
        xvb[di*3+dj] = smem[ch*180 + (li+4+di)*18 + (lj+dj)];
      }
#pragma unroll
    for (int o = 0; o < 18; ++o) {
      const float* wr = w_p + (o*C + cg)*9;
#pragma unroll
      for (int n = 0; n < 9; ++n) { accA[o] += xva[n]*wr[n]; accB[o] += xvb[n]*wr[n]; }
    }
#pragma unroll
    for (int o = 0; o < 9; ++o) {
      const float* wr = w_m + (o*C + cg)*9;
#pragma unroll
      for (int n = 0; n < 9; ++n) { accA[18+o] += xva[n]*wr[n]; accB[18+o] += xvb[n]*wr[n]; }
    }
  }

  // ---- tree reduce across csub: red[(cs*64+pl)*2+ph][28] ----
#define RED(cs,ph,o) smem[(((cs)*64 + pl)*2 + (ph))*28 + (o)]
  __syncthreads();
  if (csub >= 2) {
#pragma unroll
    for (int o = 0; o < 27; ++o) { RED(csub-2,0,o) = accA[o]; RED(csub-2,1,o) = accB[o]; }
  }
  __syncthreads();
  if (csub < 2) {
#pragma unroll
    for (int o = 0; o < 27; ++o) { accA[o] += RED(csub,0,o); accB[o] += RED(csub,1,o); }
  }
  __syncthreads();
  if (csub == 1) {
#pragma unroll
    for (int o = 0; o < 27; ++o) { RED(0,0,o) = accA[o]; RED(0,1,o) = accB[o]; }
  }
  __syncthreads();
  if (csub == 0) {
    float* pbase_ = part + ((long)(s*BATCH + b)*27)*NPIX;
    int pA = (i0+li)*W + (j0+lj);
    int pB = (i0+li+4)*W + (j0+lj);
#pragma unroll
    for (int o = 0; o < 27; ++o) {
      pbase_[(long)o*NPIX + pA] = accA[o] + RED(0,0,o);
      pbase_[(long)o*NPIX + pB] = accB[o] + RED(0,1,o);
    }
  }
#undef RED
}

// ---------------------------------------------------------------------------
// Kernel 2: pack w_conv into A-frag bf16 layout under K-permutation
// k' = n*128 + c  (so 8 consecutive k' = 8 consecutive channels, fixed n).
// wPack[kq'][oc][e], k' = kq'*8+e; n = kq'>>4, c = (kq'&15)*8+e.
// ---------------------------------------------------------------------------
__global__ __launch_bounds__(256) void wpack_kernel(
    const float* __restrict__ w_conv, unsigned short* __restrict__ wPack)
{
  int g  = blockIdx.x*256 + threadIdx.x;   // 0..18431
  int oc = g & 127;
  int kq = g >> 7;                          // 0..143
  int n  = kq >> 4;
  int c0 = (kq & 15) * 8;
  const float* src = w_conv + oc*1152 + n;
  float f[8];
#pragma unroll
  for (int e = 0; e < 8; ++e) f[e] = src[(c0+e)*9];
  unsigned p0 = (unsigned)f2bf(f[0]) | ((unsigned)f2bf(f[1])<<16);
  unsigned p1 = (unsigned)f2bf(f[2]) | ((unsigned)f2bf(f[3])<<16);
  unsigned p2 = (unsigned)f2bf(f[4]) | ((unsigned)f2bf(f[5])<<16);
  unsigned p3 = (unsigned)f2bf(f[6]) | ((unsigned)f2bf(f[7])<<16);
  *(uint4*)(wPack + (long)g*8) = make_uint4(p0,p1,p2,p3);
}

// ---------------------------------------------------------------------------
// Kernel 3: fused bilinear sampling + MFMA GEMM, NHWC gathers.
// K' chunks of 64: n = cc>>1, c-range = (cc&1)*64 + ksl8*8. Per chunk/thread:
// 1 int4 + 1 float4 metadata, 8 x float4 corner loads (vs 32 dwords in R5),
// 40 FMA lerp, bf16-pack, LDS B-frag store. Pipeline/barriers as R4/R5.
// ---------------------------------------------------------------------------
__global__ __launch_bounds__(256) void dcn_kernel(
    const float* __restrict__ xT, const float* __restrict__ part,
    const float* __restrict__ b_p, const float* __restrict__ b_m,
    const unsigned short* __restrict__ wPack, float* __restrict__ out)
{
  __shared__ int4   mIv[9*PX];
  __shared__ float4 mWv[9*PX];
  __shared__ unsigned short sP[2][8*PX*8];

  int b     = blockIdx.x >> 9;
  int pbase = (blockIdx.x & 511) * PX;
  int tid   = threadIdx.x;
  int lane  = tid & 63;
  int wid   = tid >> 6;

  // ---- phase 0: sampling metadata ----
  for (int v = tid; v < 9*PX; v += 256) {
    int px = v & (PX-1);
    int n  = v >> 5;
    int p  = pbase + px;
    int i = p >> 7, j = p & 127;

    const float* pp = part + (long)b*27*NPIX + p;
    const long ss = (long)BATCH*27*NPIX;
    float offx = b_p[n], offy = b_p[9+n], mm = b_m[n];
#pragma unroll
    for (int s = 0; s < 4; ++s) {
      offx += pp[s*ss + (long)n*NPIX];
      offy += pp[s*ss + (long)(9+n)*NPIX];
      mm   += pp[s*ss + (long)(18+n)*NPIX];
    }
    float mv = 1.f/(1.f + expf(-mm));

    float px_ = offx + (float)(i+1) + (float)(n/3 - 1);
    float py_ = offy + (float)(j+1) + (float)(n%3 - 1);
    float fx = floorf(px_), fy = floorf(py_);
    int qltx = min(max((int)fx,     0), 129);
    int qlty = min(max((int)fy,     0), 129);
    int qrbx = min(max((int)fx + 1, 0), 129);
    int qrby = min(max((int)fy + 1, 0), 129);
    px_ = fminf(fmaxf(px_, 0.f), 129.f);
    py_ = fminf(fmaxf(py_, 0.f), 129.f);
    float gxl = 1.f + ((float)qltx - px_);
    float gxr = 1.f - ((float)qrbx - px_);
    float gyl = 1.f + ((float)qlty - py_);
    float gyr = 1.f - ((float)qrby - py_);

    int   qx[4] = {qltx, qrbx, qltx, qrbx};
    int   qy[4] = {qlty, qrby, qrby, qlty};
    float gw[4] = {gxl*gyl, gxr*gyr, gxl*gyr, gxr*gyl};
    int   ii[4]; float ww[4];
#pragma unroll
    for (int cn = 0; cn < 4; ++cn) {
      bool valid = (qx[cn]>=1)&&(qx[cn]<=H)&&(qy[cn]>=1)&&(qy[cn]<=W);
      ii[cn] = valid ? ((qx[cn]-1)*W + (qy[cn]-1)) : 0;
      ww[cn] = valid ? gw[cn]*mv : 0.f;
    }
    mIv[v] = make_int4(ii[0], ii[1], ii[2], ii[3]);
    mWv[v] = make_float4(ww[0], ww[1], ww[2], ww[3]);
  }
  __syncthreads();

  f32x4 acc[2][2];
#pragma unroll
  for (int a_ = 0; a_ < 2; ++a_)
#pragma unroll
    for (int b_ = 0; b_ < 2; ++b_) acc[a_][b_] = (f32x4){0.f,0.f,0.f,0.f};

  int spx   = tid & 31;
  int ksl8  = tid >> 5;                // 0..7
  int col   = lane & 15;
  int kslot = lane >> 4;

  const float* xTb = xT + (long)b*NPIX*C;
  float4 gv[8];                        // 4 corners x 2 float4 (8 channels)
  bf16x8 aCur[2][2], aNxt[2][2];

#define ISSUE_G(CC) {                                                     \
  int n_ = (CC) >> 1;                                                     \
  int4 iv = mIv[n_*PX + spx];                                             \
  int coff = ((CC)&1)*64 + ksl8*8;                                        \
  const float* p0 = xTb + (long)iv.x*C + coff;                            \
  const float* p1 = xTb + (long)iv.y*C + coff;                            \
  const float* p2 = xTb + (long)iv.z*C + coff;                            \
  const float* p3 = xTb + (long)iv.w*C + coff;                            \
  gv[0] = *(const float4*)p0; gv[1] = *(const float4*)(p0+4);             \
  gv[2] = *(const float4*)p1; gv[3] = *(const float4*)(p1+4);             \
  gv[4] = *(const float4*)p2; gv[5] = *(const float4*)(p2+4);             \
  gv[6] = *(const float4*)p3; gv[7] = *(const float4*)(p3+4); }

#define GC(cn, j) (((const float*)&gv[(cn)*2 + ((j)>>2)])[(j)&3])

#define COMPUTE_S(CC, BUF) {                                              \
  int n_ = (CC) >> 1;                                                     \
  float4 wv = mWv[n_*PX + spx];                                           \
  unsigned pk[4];                                                         \
  _Pragma("unroll")                                                       \
  for (int jp = 0; jp < 4; ++jp) {                                        \
    float s0 = wv.x*GC(0,jp*2)   + wv.y*GC(1,jp*2)                        \
             + wv.z*GC(2,jp*2)   + wv.w*GC(3,jp*2);                       \
    float s1 = wv.x*GC(0,jp*2+1) + wv.y*GC(1,jp*2+1)                      \
             + wv.z*GC(2,jp*2+1) + wv.w*GC(3,jp*2+1);                     \
    pk[jp] = (unsigned)f2bf(s0) | ((unsigned)f2bf(s1)<<16);               \
  }                                                                       \
  *(uint4*)&sP[BUF][(ksl8*PX + spx)*8] = make_uint4(pk[0],pk[1],pk[2],pk[3]); }

#define ISSUE_A(CC, DST) { _Pragma("unroll")                              \
  for (int st = 0; st < 2; ++st) { _Pragma("unroll")                      \
    for (int o2 = 0; o2 < 2; ++o2) {                                      \
      int kq = (CC)*8 + st*4 + kslot;                                     \
      int oc = wid*32 + o2*16 + col;                                      \
      DST[st][o2] = *(const bf16x8*)(wPack + ((long)kq*128 + oc)*8);      \
    } } }

#define BARRIER {                                                         \
  __builtin_amdgcn_sched_barrier(0);                                      \
  asm volatile("s_waitcnt lgkmcnt(0)" ::: "memory");                      \
  __builtin_amdgcn_sched_barrier(0);                                      \
  __builtin_amdgcn_s_barrier();                                           \
  __builtin_amdgcn_sched_barrier(0); }

#define DO_MFMA(BUF, AFR) { _Pragma("unroll")                             \
  for (int st = 0; st < 2; ++st) {                                        \
    bf16x8 b0 = *(const bf16x8*)&sP[BUF][((st*4+kslot)*PX +      col)*8]; \
    bf16x8 b1 = *(const bf16x8*)&sP[BUF][((st*4+kslot)*PX + 16 + col)*8]; \
    acc[0][0] = __builtin_amdgcn_mfma_f32_16x16x32_bf16(AFR[st][0], b0, acc[0][0], 0,0,0); \
    acc[0][1] = __builtin_amdgcn_mfma_f32_16x16x32_bf16(AFR[st][0], b1, acc[0][1], 0,0,0); \
    acc[1][0] = __builtin_amdgcn_mfma_f32_16x16x32_bf16(AFR[st][1], b0, acc[1][0], 0,0,0); \
    acc[1][1] = __builtin_amdgcn_mfma_f32_16x16x32_bf16(AFR[st][1], b1, acc[1][1], 0,0,0); \
  } }

  ISSUE_G(0)
  ISSUE_A(0, aCur)

  for (int cc2 = 0; cc2 < 9; ++cc2) {
    int ccE = cc2*2, ccO = cc2*2 + 1;

    COMPUTE_S(ccE, 0)                  // waits on gv(ccE)
    ISSUE_G(ccO)                       // in flight across barrier
    BARRIER
    ISSUE_A(ccO, aNxt)
    DO_MFMA(0, aCur)

    COMPUTE_S(ccO, 1)
    if (cc2 < 8) { ISSUE_G(ccE+2) }
    BARRIER
    if (cc2 < 8) { ISSUE_A(ccE+2, aCur) }
    DO_MFMA(1, aNxt)
  }
#undef ISSUE_G
#undef GC
#undef COMPUTE_S
#undef ISSUE_A
#undef BARRIER
#undef DO_MFMA

  // ---- epilogue ----
  int row4 = (lane >> 4) * 4;
#pragma unroll
  for (int o2 = 0; o2 < 2; ++o2)
#pragma unroll
    for (int p2 = 0; p2 < 2; ++p2)
#pragma unroll
      for (int r = 0; r < 4; ++r) {
        int oc = wid*32 + o2*16 + row4 + r;
        int px = pbase + p2*16 + col;
        out[((long)(b*C + oc))*NPIX + px] = acc[o2][p2][r];
      }
}

// ---------------------------------------------------------------------------
extern "C" void kernel_launch(void* const* d_in, const int* in_sizes, int n_in,
                              void* d_out, int out_size, void* d_ws, size_t ws_size,
                              hipStream_t stream) {
  const float* x      = (const float*)d_in[0];
  const float* w_p    = (const float*)d_in[1];
  const float* b_p    = (const float*)d_in[2];
  const float* w_m    = (const float*)d_in[3];
  const float* b_m    = (const float*)d_in[4];
  const float* w_conv = (const float*)d_in[5];
  float* out = (float*)d_out;
  float* part          = (float*)d_ws;
  unsigned short* wPk  = (unsigned short*)((char*)d_ws + WS_WPK_OFF);
  float* xT            = (float*)((char*)d_ws + WS_XT_OFF);   // 16.78 MB, total 31.2 MB

  conv27_kernel<<<1024, 256, 0, stream>>>(x, w_p, w_m, part, xT);
  wpack_kernel<<<72, 256, 0, stream>>>(w_conv, wPk);
  dcn_kernel<<<1024, 256, 0, stream>>>(xT, part, b_p, b_m, wPk, out);
}